// Round 5
// baseline (80.867 us; speedup 1.0000x reference)
//
#include <hip/hip_runtime.h>

// Problem constants
#define LSEQ 1024
#define NBATCH 2
#define NH 16
#define HDIM 64
#define WWIN 64
#define M_GEMM 2048   // NBATCH*LSEQ
#define K_GEMM 1024
#define N_GEMM 1024

// GEMM tile
#define BN 128
#define BK 32

typedef __bf16 bf16x8 __attribute__((ext_vector_type(8)));
typedef float f32x4 __attribute__((ext_vector_type(4)));

typedef __attribute__((address_space(1))) const unsigned int gas_uint;
typedef __attribute__((address_space(3))) unsigned int las_uint;

__device__ __forceinline__ unsigned short f2bf(float f) {
  unsigned int u = __float_as_uint(f);
  u += 0x7fff + ((u >> 16) & 1);   // round-to-nearest-even
  return (unsigned short)(u >> 16);
}
__device__ __forceinline__ float bf2f(unsigned short h) {
  return __uint_as_float(((unsigned int)h) << 16);
}

union BF8 { bf16x8 v; unsigned short u[8]; };

// ---- pre-pass: fp32 -> bf16 cast (blocks 0..2047) + trig table (2048..2175)
__global__ void prep_k(const float* __restrict__ src,
                       unsigned short* __restrict__ dst,
                       const float* __restrict__ freqs,
                       float* __restrict__ ctab, float* __restrict__ stab) {
  const int bid = blockIdx.x;
  if (bid < 2048) {
    const int i = bid * 256 + threadIdx.x;
    const float4 v = reinterpret_cast<const float4*>(src)[i];
    ushort4 o;
    o.x = f2bf(v.x); o.y = f2bf(v.y); o.z = f2bf(v.z); o.w = f2bf(v.w);
    reinterpret_cast<ushort4*>(dst)[i] = o;
  } else {
    const int i = (bid - 2048) * 256 + threadIdx.x;  // 0..32767
    float s, c;
    sincosf(freqs[i], &s, &c);
    ctab[i] = c;
    stab[i] = s;
  }
}

// ---------------- pre-pass: W (KxN f32) -> W^T (NxK bf16), 4 mats fused ---
__global__ void transpose_w_k(const float* __restrict__ W0,
                              const float* __restrict__ W1,
                              const float* __restrict__ W2,
                              const float* __restrict__ W3,
                              unsigned short* __restrict__ dst0) {
  __shared__ float tile[32][33];
  const int z = blockIdx.z;
  const float* src = (z == 0) ? W0 : (z == 1) ? W1 : (z == 2) ? W2 : W3;
  unsigned short* dst = dst0 + ((size_t)z << 20);
  const int n0 = blockIdx.x * 32, k0 = blockIdx.y * 32;
  const int tx = threadIdx.x, ty = threadIdx.y;
#pragma unroll
  for (int i = 0; i < 32; i += 8)
    tile[ty + i][tx] = src[(size_t)(k0 + ty + i) * 1024 + n0 + tx];
  __syncthreads();
#pragma unroll
  for (int i = 0; i < 32; i += 8)
    dst[(size_t)(n0 + ty + i) * 1024 + k0 + tx] = f2bf(tile[tx][ty + i]);
}

// ---------------- GEMM: C = A(MxK) * B(KxN), A bf16 row-major, Bt = B^T (NxK) bf16
// Double-buffered LDS, 2-phase pipeline: issue next-tile global_load_lds
// BEFORE computing current tile; single __syncthreads per K-step (its
// vmcnt+lgkm drain is the counted wait -- loads fly during compute).
// MODE 0: epilogue applies RoPE (z<2, trig table), scatters fp32 head-major.
// MODE 1: epilogue writes fp32 row-major MxN (final output).
__device__ __forceinline__ void gload16(const void* g, void* l) {
  __builtin_amdgcn_global_load_lds((gas_uint*)g, (las_uint*)l, 16, 0, 0);
}

template <int MODE, int TBM>
__global__ __launch_bounds__(256, 2) void gemm_bf16_k(
    const unsigned short* __restrict__ A,
    const unsigned short* __restrict__ Bt0,
    float* __restrict__ C0,
    const float* __restrict__ ctab,
    const float* __restrict__ stab) {
  constexpr int NBM = M_GEMM / TBM;
  constexpr int WN = (TBM == 128) ? 2 : 4;   // waves along N
  constexpr int NJ = 8 / WN;                 // 16-col frags per wave
  constexpr int ASZ = TBM * BK;              // elements per A buffer
  constexpr int BSZ = BN * BK;
  constexpr int NT = K_GEMM / BK;            // 32 K-steps
  __shared__ unsigned short sA[2 * ASZ];
  __shared__ unsigned short sB[2 * BSZ];

  const int tid = threadIdx.x;
  const int lane = tid & 63;
  const int wave = tid >> 6;           // 0..3
  const int wm = (TBM == 128) ? (wave >> 1) : 0;
  const int wn = (TBM == 128) ? (wave & 1) : wave;

  const int bm = blockIdx.x % NBM;
  const int bn = blockIdx.x / NBM;
  const int z = blockIdx.z;

  const unsigned short* Bt = Bt0 + (size_t)z * ((size_t)N_GEMM * K_GEMM);
  const int m0 = bm * TBM, n0 = bn * BN;

  const int srow = lane >> 2;          // 0..15
  const int skoff = (lane & 3) * 8;    // 0/8/16/24 elements

  const unsigned short* gA0 = A + (size_t)(m0 + wave * 16 + srow) * K_GEMM + skoff;
  const unsigned short* gA1 = A + (size_t)(m0 + 64 + wave * 16 + srow) * K_GEMM + skoff;
  const unsigned short* gB0 = Bt + (size_t)(n0 + wave * 16 + srow) * K_GEMM + skoff;
  const unsigned short* gB1 = Bt + (size_t)(n0 + 64 + wave * 16 + srow) * K_GEMM + skoff;

  unsigned short* lA0 = &sA[(wave * 16) * BK];
  unsigned short* lA1 = &sA[(64 + wave * 16) * BK];
  unsigned short* lB0 = &sB[(wave * 16) * BK];
  unsigned short* lB1 = &sB[(64 + wave * 16) * BK];

  f32x4 acc[4][NJ] = {};

  const int fr = lane & 15;
  const int fk = (lane >> 4) * 8;

  // prologue: stage tile 0 into buffer 0
  gload16(gA0, lA0);
  if constexpr (TBM == 128) gload16(gA1, lA1);
  gload16(gB0, lB0);
  gload16(gB1, lB1);
  __syncthreads();

#pragma unroll 2
  for (int t = 0; t < NT; ++t) {
    const int cur = t & 1;
    const int nxt = cur ^ 1;
    if (t + 1 < NT) {                 // stage next tile early (overlaps compute)
      const int kt = (t + 1) * BK;
      gload16(gA0 + kt, lA0 + nxt * ASZ);
      if constexpr (TBM == 128) gload16(gA1 + kt, lA1 + nxt * ASZ);
      gload16(gB0 + kt, lB0 + nxt * BSZ);
      gload16(gB1 + kt, lB1 + nxt * BSZ);
    }
    const unsigned short* cA = sA + cur * ASZ;
    const unsigned short* cB = sB + cur * BSZ;
    bf16x8 af[4], bfr[NJ];
#pragma unroll
    for (int i = 0; i < 4; i++)
      af[i] = *reinterpret_cast<const bf16x8*>(&cA[(wm * 64 + i * 16 + fr) * BK + fk]);
#pragma unroll
    for (int j = 0; j < NJ; j++)
      bfr[j] = *reinterpret_cast<const bf16x8*>(&cB[(wn * (NJ * 16) + j * 16 + fr) * BK + fk]);
#pragma unroll
    for (int i = 0; i < 4; i++)
#pragma unroll
      for (int j = 0; j < NJ; j++)
        acc[i][j] = __builtin_amdgcn_mfma_f32_16x16x32_bf16(af[i], bfr[j], acc[i][j], 0, 0, 0);
    __syncthreads();   // drains vmcnt (next tile staged) + frees cur buffer
  }

  float* C = C0 + (MODE == 0 ? (size_t)z * ((size_t)M_GEMM * N_GEMM) : (size_t)0);
  const int fq = lane >> 4;
  const bool dorope = (MODE == 0) && (z < 2);
#pragma unroll
  for (int i = 0; i < 4; i++) {
#pragma unroll
    for (int j = 0; j < NJ; j++) {
#pragma unroll
      for (int r = 0; r < 4; r++) {
        const int row = m0 + wm * 64 + i * 16 + fq * 4 + r;
        const int col = n0 + wn * (NJ * 16) + j * 16 + fr;
        float v = acc[i][j][r];
        if (MODE == 0) {
          const int l = row & 1023, d = col & 63;
          if (dorope) {
            // pair partner (d^1) lives in lane^1 (same i,j,r)
            const float other = __shfl_xor(v, 1);
            const int ti = (l << 5) + (d >> 1);
            const float c = ctab[ti], s = stab[ti];
            v = (d & 1) ? (other * s + v * c) : (v * c - other * s);
          }
          const int b = row >> 10, h = col >> 6;
          C[((((size_t)b * NH + h) * LSEQ + l) << 6) + d] = v;
        } else {
          C[(size_t)row * N_GEMM + col] = v;
        }
      }
    }
  }
}

// ---------------- local windowed attention v3 (MFMA) ----------------------
// Block = (bh, 64-query tile). K span rows j=0..127 map to key l = lb-64+j
// (zero-filled for l<0 -> reproduces reference zero-pad softmax semantics).
// Scores S[rt][j] via mfma(Q, K^T) with hi/lo split-bf16 (score err ~2^-17).
// Softmax row-masked to j in [rt+1, rt+64]. P (bf16) -> LDS -> A-frags.
// V staged transposed (Vt[d][j] bf16) for B-frags. All LDS XOR-swizzled.
__device__ __forceinline__ int kaddr(int j, int d) {   // Ks: 128 rows x 128B
  return j * 128 + ((((d >> 3) ^ (j & 7)) & 7) << 4) + ((d & 7) << 1);
}
__device__ __forceinline__ int taddr(int r, int c) {   // Vt/Ps: 64 rows x 256B
  return r * 256 + ((((c >> 3) ^ (r & 7)) & 15) << 4) + ((c & 7) << 1);
}

__global__ __launch_bounds__(256, 2) void local_attn3_k(
    const float* __restrict__ Q, const float* __restrict__ Kg,
    const float* __restrict__ Vg, unsigned short* __restrict__ O) {
  __shared__ __align__(16) unsigned char KsH[16384];
  __shared__ __align__(16) unsigned char KsL[16384];
  __shared__ __align__(16) unsigned char VtB[16384];
  __shared__ __align__(16) unsigned char PsB[16384];

  const int tid = threadIdx.x;
  const int lane = tid & 63;
  const int wave = tid >> 6;
  const int lr = lane & 15;        // fragment row/col index
  const int lg = lane >> 4;        // 0..3 lane group
  const int bh = blockIdx.x >> 4;
  const int lb = (blockIdx.x & 15) << 6;

  const float* Kb = Kg + ((size_t)bh << 16);
  const float* Vb = Vg + ((size_t)bh << 16);

  // ---- stage K span as hi/lo bf16, swizzled ----
#pragma unroll
  for (int i = 0; i < 8; ++i) {
    const int item = i * 256 + tid;       // 0..2047
    const int j = item >> 4;              // 0..127
    const int d0 = (item & 15) << 2;      // 0..60
    const int g = lb - 64 + j;
    float4 kv = make_float4(0.f, 0.f, 0.f, 0.f);
    if (g >= 0) kv = *reinterpret_cast<const float4*>(&Kb[((size_t)g << 6) + d0]);
    ushort4 hh, ll;
    hh.x = f2bf(kv.x); ll.x = f2bf(kv.x - bf2f(hh.x));
    hh.y = f2bf(kv.y); ll.y = f2bf(kv.y - bf2f(hh.y));
    hh.z = f2bf(kv.z); ll.z = f2bf(kv.z - bf2f(hh.z));
    hh.w = f2bf(kv.w); ll.w = f2bf(kv.w - bf2f(hh.w));
    *reinterpret_cast<ushort4*>(KsH + kaddr(j, d0)) = hh;
    *reinterpret_cast<ushort4*>(KsL + kaddr(j, d0)) = ll;
  }

  // ---- stage V transposed: Vt[d][j] bf16, packed pair writes ----
#pragma unroll
  for (int p = 0; p < 4; ++p) {
    const int item = p * 256 + tid;       // 0..1023
    const int jp = item >> 4;             // 0..63 (pair of j)
    const int d0 = (item & 15) << 2;      // 0..60
    const int g0 = lb - 64 + 2 * jp;
    float4 va = make_float4(0.f, 0.f, 0.f, 0.f);
    float4 vb = make_float4(0.f, 0.f, 0.f, 0.f);
    if (g0 >= 0) va = *reinterpret_cast<const float4*>(&Vb[((size_t)g0 << 6) + d0]);
    if (g0 + 1 >= 0) vb = *reinterpret_cast<const float4*>(&Vb[((size_t)(g0 + 1) << 6) + d0]);
    const float aa[4] = {va.x, va.y, va.z, va.w};
    const float bb[4] = {vb.x, vb.y, vb.z, vb.w};
#pragma unroll
    for (int e = 0; e < 4; ++e) {
      const unsigned int pk = (unsigned int)f2bf(aa[e]) | ((unsigned int)f2bf(bb[e]) << 16);
      *reinterpret_cast<unsigned int*>(VtB + taddr(d0 + e, 2 * jp)) = pk;
    }
  }
  __syncthreads();

  // ---- Q fragments (hi/lo split, scale folded in) ----
  const int rtbase = wave * 16;
  const float* qrow = Q + ((size_t)bh << 16) + ((size_t)(lb + rtbase + lr) << 6);
  BF8 qh[2], ql[2];
#pragma unroll
  for (int ks = 0; ks < 2; ++ks) {
    const int d0 = ks * 32 + lg * 8;
    const float4 a = *reinterpret_cast<const float4*>(&qrow[d0]);
    const float4 b = *reinterpret_cast<const float4*>(&qrow[d0 + 4]);
    const float vv[8] = {a.x, a.y, a.z, a.w, b.x, b.y, b.z, b.w};
#pragma unroll
    for (int e = 0; e < 8; ++e) {
      const float v = vv[e] * 0.125f;
      const unsigned short h = f2bf(v);
      qh[ks].u[e] = h;
      ql[ks].u[e] = f2bf(v - bf2f(h));
    }
  }

  // ---- scores: S[rt][j], wave owns rows rtbase..rtbase+15, all 128 j ----
  f32x4 acc[8] = {};
#pragma unroll
  for (int ks = 0; ks < 2; ++ks) {
    const int d0 = ks * 32 + lg * 8;
#pragma unroll
    for (int nt = 0; nt < 8; ++nt) {
      const int j = nt * 16 + lr;
      const bf16x8 kh = *reinterpret_cast<const bf16x8*>(KsH + kaddr(j, d0));
      const bf16x8 kl = *reinterpret_cast<const bf16x8*>(KsL + kaddr(j, d0));
      acc[nt] = __builtin_amdgcn_mfma_f32_16x16x32_bf16(qh[ks].v, kh, acc[nt], 0, 0, 0);
      acc[nt] = __builtin_amdgcn_mfma_f32_16x16x32_bf16(ql[ks].v, kh, acc[nt], 0, 0, 0);
      acc[nt] = __builtin_amdgcn_mfma_f32_16x16x32_bf16(qh[ks].v, kl, acc[nt], 0, 0, 0);
    }
  }

  // ---- masked softmax per row (rows live in 16-lane groups) ----
  float sum4[4];
#pragma unroll
  for (int reg = 0; reg < 4; ++reg) {
    const int rt = rtbase + lg * 4 + reg;
    float m = -3.0e38f;
#pragma unroll
    for (int nt = 0; nt < 8; ++nt) {
      const int j = nt * 16 + lr;
      const bool valid = (j > rt) && (j <= rt + 64);
      const float sv = valid ? acc[nt][reg] : -3.0e38f;
      acc[nt][reg] = sv;
      m = fmaxf(m, sv);
    }
    m = fmaxf(m, __shfl_xor(m, 1));
    m = fmaxf(m, __shfl_xor(m, 2));
    m = fmaxf(m, __shfl_xor(m, 4));
    m = fmaxf(m, __shfl_xor(m, 8));
    float s = 0.f;
#pragma unroll
    for (int nt = 0; nt < 8; ++nt) {
      const float p = (acc[nt][reg] > -1.0e37f) ? __expf(acc[nt][reg] - m) : 0.f;
      acc[nt][reg] = p;
      s += p;
    }
    s += __shfl_xor(s, 1);
    s += __shfl_xor(s, 2);
    s += __shfl_xor(s, 4);
    s += __shfl_xor(s, 8);
    sum4[reg] = s;
  }

  // ---- write P (bf16, swizzled; wave-private rows, no barrier needed) ----
#pragma unroll
  for (int nt = 0; nt < 8; ++nt)
#pragma unroll
    for (int reg = 0; reg < 4; ++reg) {
      const int rt = rtbase + lg * 4 + reg;
      const int j = nt * 16 + lr;
      *reinterpret_cast<unsigned short*>(PsB + taddr(rt, j)) = f2bf(acc[nt][reg]);
    }

  // ---- PV: out[rt][d] = sum_j P[rt][j] * V[j][d] ----
  f32x4 oacc[4] = {};
#pragma unroll
  for (int ks = 0; ks < 4; ++ks) {
    const int j0 = ks * 32 + lg * 8;
    const bf16x8 pa = *reinterpret_cast<const bf16x8*>(PsB + taddr(rtbase + lr, j0));
#pragma unroll
    for (int nt = 0; nt < 4; ++nt) {
      const int d = nt * 16 + lr;
      const bf16x8 vf = *reinterpret_cast<const bf16x8*>(VtB + taddr(d, j0));
      oacc[nt] = __builtin_amdgcn_mfma_f32_16x16x32_bf16(pa, vf, oacc[nt], 0, 0, 0);
    }
  }

  // ---- normalize + write out (bf16, [b][l][h*64+d]) ----
  const int b = bh >> 4, h = bh & 15;
#pragma unroll
  for (int nt = 0; nt < 4; ++nt)
#pragma unroll
    for (int reg = 0; reg < 4; ++reg) {
      const int rt = rtbase + lg * 4 + reg;
      const int d = nt * 16 + lr;
      const float o = oacc[nt][reg] / sum4[reg];
      const int lq = lb + rt;
      O[(((size_t)b * LSEQ + lq) << 10) + (h << 6) + d] = f2bf(o);
    }
}

// ---------------- launch ----------------
extern "C" void kernel_launch(void* const* d_in, const int* in_sizes, int n_in,
                              void* d_out, int out_size, void* d_ws, size_t ws_size,
                              hipStream_t stream) {
  const float* x     = (const float*)d_in[0];
  const float* freqs = (const float*)d_in[1];
  const float* Wq    = (const float*)d_in[2];
  const float* Wk    = (const float*)d_in[3];
  const float* Wv    = (const float*)d_in[4];
  const float* Wo    = (const float*)d_in[5];
  float* out = (float*)d_out;
  char* ws = (char*)d_ws;

  // workspace layout (40 MB total)
  unsigned short* xb  = (unsigned short*)ws;                   // 4 MB: x bf16 [2048][1024]
  unsigned short* Wt  = (unsigned short*)(ws + (4u << 20));    // 8 MB: W^T bf16 x4
  float* QKV          = (float*)(ws + (12u << 20));            // 24 MB: Q,K,V fp32 head-major
  unsigned short* Oat = (unsigned short*)(ws + (36u << 20));   // 4 MB: attn out bf16
  // trig tables live past Oat (dead once QKV GEMM finishes; attn overwrites
  // is impossible there -- they sit in the last 256 KB after Oat's 4 MB? No:
  // keep them inside the Oat region tail, freed before attn writes Oat).
  float* ctab = (float*)(ws + (36u << 20) + (1u << 21));       // 128 KB
  float* stab = ctab + 32768;                                  // 128 KB

  prep_k<<<2176, 256, 0, stream>>>(x, xb, freqs, ctab, stab);
  transpose_w_k<<<dim3(32, 32, 4), dim3(32, 8), 0, stream>>>(Wq, Wk, Wv, Wo, Wt);

  // Q,K,V = x @ {Wq,Wk,Wv} with fused RoPE (z<2), scattered to head-major fp32
  gemm_bf16_k<0, 128><<<dim3(128, 1, 3), 256, 0, stream>>>(xb, Wt, QKV, ctab, stab);

  // local attention -> bf16 [B*L][D_MODEL]
  local_attn3_k<<<512, 256, 0, stream>>>(QKV, QKV + (1u << 21), QKV + (2u << 21), Oat);

  // final projection -> fp32 d_out (64x128 tiles -> 256 workgroups, 1/CU)
  gemm_bf16_k<1, 64><<<dim3(256, 1, 1), 256, 0, stream>>>(Oat, Wt + (3u << 20), out, ctab, stab);
}

// Round 6
// 75.299 us; speedup vs baseline: 1.0739x; 1.0739x over previous
//
#include <hip/hip_runtime.h>

// Problem constants
#define LSEQ 1024
#define NBATCH 2
#define NH 16
#define HDIM 64
#define WWIN 64
#define M_GEMM 2048   // NBATCH*LSEQ
#define K_GEMM 1024
#define N_GEMM 1024

// GEMM tile
#define BN 128
#define BK 32

typedef __bf16 bf16x8 __attribute__((ext_vector_type(8)));
typedef float f32x4 __attribute__((ext_vector_type(4)));

typedef __attribute__((address_space(1))) const unsigned int gas_uint;
typedef __attribute__((address_space(3))) unsigned int las_uint;

__device__ __forceinline__ unsigned short f2bf(float f) {
  unsigned int u = __float_as_uint(f);
  u += 0x7fff + ((u >> 16) & 1);   // round-to-nearest-even
  return (unsigned short)(u >> 16);
}
__device__ __forceinline__ float bf2f(unsigned short h) {
  return __uint_as_float(((unsigned int)h) << 16);
}

union BF8 { bf16x8 v; unsigned short u[8]; };

// ---- fused pre-pass: x cast (blocks 0..2047), trig table (2048..2175),
// ---- W transposes (2176..6271: 4 mats x 1024 32x32 tiles)
__global__ void prep_all_k(const float* __restrict__ x,
                           unsigned short* __restrict__ xb,
                           const float* __restrict__ freqs,
                           float* __restrict__ ctab, float* __restrict__ stab,
                           const float* __restrict__ W0,
                           const float* __restrict__ W1,
                           const float* __restrict__ W2,
                           const float* __restrict__ W3,
                           unsigned short* __restrict__ Wt) {
  __shared__ float tile[32][33];
  const int bid = blockIdx.x;
  const int tid = threadIdx.x;
  if (bid < 2048) {
    const int i = bid * 256 + tid;
    const float4 v = reinterpret_cast<const float4*>(x)[i];
    ushort4 o;
    o.x = f2bf(v.x); o.y = f2bf(v.y); o.z = f2bf(v.z); o.w = f2bf(v.w);
    reinterpret_cast<ushort4*>(xb)[i] = o;
  } else if (bid < 2176) {
    const int i = (bid - 2048) * 256 + tid;  // 0..32767
    float s, c;
    sincosf(freqs[i], &s, &c);
    ctab[i] = c;
    stab[i] = s;
  } else {
    const int t = bid - 2176;
    const int z = t >> 10;
    const float* src = (z == 0) ? W0 : (z == 1) ? W1 : (z == 2) ? W2 : W3;
    unsigned short* dst = Wt + ((size_t)z << 20);
    const int rem = t & 1023;
    const int n0 = (rem & 31) << 5, k0 = (rem >> 5) << 5;
    const int tx = tid & 31, ty = tid >> 5;   // 32 x 8
#pragma unroll
    for (int i = 0; i < 32; i += 8)
      tile[ty + i][tx] = src[(size_t)(k0 + ty + i) * 1024 + n0 + tx];
    __syncthreads();
#pragma unroll
    for (int i = 0; i < 32; i += 8)
      dst[(size_t)(n0 + ty + i) * 1024 + k0 + tx] = f2bf(tile[tx][ty + i]);
  }
}

// ---------------- GEMM: C = A(MxK) * B(KxN), A bf16 row-major, Bt = B^T (NxK) bf16
// Double-buffered LDS, 2-phase pipeline. LDS chunk-XOR swizzle (T2, m173
// pattern): linear LDS dest for global_load_lds + PRE-SWIZZLED global source
// + swizzled fragment read. phys_chunk = chunk ^ ((row>>1)&3) turns the
// 8-way ds_read_b128 bank conflict of the [row][BK] layout into free 2-way.
// MODE 0: epilogue applies RoPE (z<2, trig table), scatters fp32 head-major.
// MODE 1: epilogue writes fp32 row-major MxN (final output).
__device__ __forceinline__ void gload16(const void* g, void* l) {
  __builtin_amdgcn_global_load_lds((gas_uint*)g, (las_uint*)l, 16, 0, 0);
}

template <int MODE, int TBM>
__global__ __launch_bounds__(256, 2) void gemm_bf16_k(
    const unsigned short* __restrict__ A,
    const unsigned short* __restrict__ Bt0,
    float* __restrict__ C0,
    const float* __restrict__ ctab,
    const float* __restrict__ stab) {
  constexpr int NBM = M_GEMM / TBM;
  constexpr int WN = (TBM == 128) ? 2 : 4;   // waves along N
  constexpr int NJ = 8 / WN;                 // 16-col frags per wave
  constexpr int ASZ = TBM * BK;              // elements per A buffer
  constexpr int BSZ = BN * BK;
  constexpr int NT = K_GEMM / BK;            // 32 K-steps
  __shared__ unsigned short sA[2 * ASZ];
  __shared__ unsigned short sB[2 * BSZ];

  const int tid = threadIdx.x;
  const int lane = tid & 63;
  const int wave = tid >> 6;           // 0..3
  const int wm = (TBM == 128) ? (wave >> 1) : 0;
  const int wn = (TBM == 128) ? (wave & 1) : wave;

  const int bm = blockIdx.x % NBM;
  const int bn = blockIdx.x / NBM;
  const int z = blockIdx.z;

  const unsigned short* Bt = Bt0 + (size_t)z * ((size_t)N_GEMM * K_GEMM);
  const int m0 = bm * TBM, n0 = bn * BN;

  // staging: row-group row srow, chunk ck; SOURCE k-chunk is swizzled so the
  // linear LDS image holds phys_chunk = global_chunk ^ ((row>>1)&3).
  const int srow = lane >> 2;                         // 0..15
  const int skoff = ((lane & 3) ^ ((srow >> 1) & 3)) * 8;  // swizzled src k-offset

  const unsigned short* gA0 = A + (size_t)(m0 + wave * 16 + srow) * K_GEMM + skoff;
  const unsigned short* gA1 = A + (size_t)(m0 + 64 + wave * 16 + srow) * K_GEMM + skoff;
  const unsigned short* gB0 = Bt + (size_t)(n0 + wave * 16 + srow) * K_GEMM + skoff;
  const unsigned short* gB1 = Bt + (size_t)(n0 + 64 + wave * 16 + srow) * K_GEMM + skoff;

  unsigned short* lA0 = &sA[(wave * 16) * BK];
  unsigned short* lA1 = &sA[(64 + wave * 16) * BK];
  unsigned short* lB0 = &sB[(wave * 16) * BK];
  unsigned short* lB1 = &sB[(64 + wave * 16) * BK];

  f32x4 acc[4][NJ] = {};

  const int fr = lane & 15;
  const int lg = lane >> 4;
  const int fswz = ((lg ^ ((fr >> 1) & 3)) * 8);      // swizzled read k-offset

  // prologue: stage tile 0 into buffer 0
  gload16(gA0, lA0);
  if constexpr (TBM == 128) gload16(gA1, lA1);
  gload16(gB0, lB0);
  gload16(gB1, lB1);
  __syncthreads();

#pragma unroll 2
  for (int t = 0; t < NT; ++t) {
    const int cur = t & 1;
    const int nxt = cur ^ 1;
    if (t + 1 < NT) {                 // stage next tile early (overlaps compute)
      const int kt = (t + 1) * BK;
      gload16(gA0 + kt, lA0 + nxt * ASZ);
      if constexpr (TBM == 128) gload16(gA1 + kt, lA1 + nxt * ASZ);
      gload16(gB0 + kt, lB0 + nxt * BSZ);
      gload16(gB1 + kt, lB1 + nxt * BSZ);
    }
    const unsigned short* cA = sA + cur * ASZ;
    const unsigned short* cB = sB + cur * BSZ;
    bf16x8 af[4], bfr[NJ];
#pragma unroll
    for (int i = 0; i < 4; i++)
      af[i] = *reinterpret_cast<const bf16x8*>(&cA[(wm * 64 + i * 16 + fr) * BK + fswz]);
#pragma unroll
    for (int j = 0; j < NJ; j++)
      bfr[j] = *reinterpret_cast<const bf16x8*>(&cB[(wn * (NJ * 16) + j * 16 + fr) * BK + fswz]);
#pragma unroll
    for (int i = 0; i < 4; i++)
#pragma unroll
      for (int j = 0; j < NJ; j++)
        acc[i][j] = __builtin_amdgcn_mfma_f32_16x16x32_bf16(af[i], bfr[j], acc[i][j], 0, 0, 0);
    __syncthreads();   // drains vmcnt (next tile staged) + frees cur buffer
  }

  float* C = C0 + (MODE == 0 ? (size_t)z * ((size_t)M_GEMM * N_GEMM) : (size_t)0);
  const int fq = lane >> 4;
  const bool dorope = (MODE == 0) && (z < 2);
#pragma unroll
  for (int i = 0; i < 4; i++) {
#pragma unroll
    for (int j = 0; j < NJ; j++) {
#pragma unroll
      for (int r = 0; r < 4; r++) {
        const int row = m0 + wm * 64 + i * 16 + fq * 4 + r;
        const int col = n0 + wn * (NJ * 16) + j * 16 + fr;
        float v = acc[i][j][r];
        if (MODE == 0) {
          const int l = row & 1023, d = col & 63;
          if (dorope) {
            // pair partner (d^1) lives in lane^1 (same i,j,r)
            const float other = __shfl_xor(v, 1);
            const int ti = (l << 5) + (d >> 1);
            const float c = ctab[ti], s = stab[ti];
            v = (d & 1) ? (other * s + v * c) : (v * c - other * s);
          }
          const int b = row >> 10, h = col >> 6;
          C[((((size_t)b * NH + h) * LSEQ + l) << 6) + d] = v;
        } else {
          C[(size_t)row * N_GEMM + col] = v;
        }
      }
    }
  }
}

// ---------------- local windowed attention v3 (MFMA) ----------------------
// Block = (bh, 64-query tile). K span rows j=0..127 map to key l = lb-64+j
// (zero-filled for l<0 -> reproduces reference zero-pad softmax semantics).
// Scores S[rt][j] via mfma(Q, K^T) with hi/lo split-bf16 (score err ~2^-17).
// Softmax row-masked to j in [rt+1, rt+64]. P (bf16) -> LDS -> A-frags.
// V staged transposed (Vt[d][j] bf16) for B-frags. All LDS XOR-swizzled.
__device__ __forceinline__ int kaddr(int j, int d) {   // Ks: 128 rows x 128B
  return j * 128 + ((((d >> 3) ^ (j & 7)) & 7) << 4) + ((d & 7) << 1);
}
__device__ __forceinline__ int taddr(int r, int c) {   // Vt/Ps: 64 rows x 256B
  return r * 256 + ((((c >> 3) ^ (r & 7)) & 15) << 4) + ((c & 7) << 1);
}

__global__ __launch_bounds__(256, 2) void local_attn3_k(
    const float* __restrict__ Q, const float* __restrict__ Kg,
    const float* __restrict__ Vg, unsigned short* __restrict__ O) {
  __shared__ __align__(16) unsigned char KsH[16384];
  __shared__ __align__(16) unsigned char KsL[16384];
  __shared__ __align__(16) unsigned char VtB[16384];
  __shared__ __align__(16) unsigned char PsB[16384];

  const int tid = threadIdx.x;
  const int lane = tid & 63;
  const int wave = tid >> 6;
  const int lr = lane & 15;        // fragment row/col index
  const int lg = lane >> 4;        // 0..3 lane group
  const int bh = blockIdx.x >> 4;
  const int lb = (blockIdx.x & 15) << 6;

  const float* Kb = Kg + ((size_t)bh << 16);
  const float* Vb = Vg + ((size_t)bh << 16);

  // ---- stage K span as hi/lo bf16, swizzled ----
#pragma unroll
  for (int i = 0; i < 8; ++i) {
    const int item = i * 256 + tid;       // 0..2047
    const int j = item >> 4;              // 0..127
    const int d0 = (item & 15) << 2;      // 0..60
    const int g = lb - 64 + j;
    float4 kv = make_float4(0.f, 0.f, 0.f, 0.f);
    if (g >= 0) kv = *reinterpret_cast<const float4*>(&Kb[((size_t)g << 6) + d0]);
    ushort4 hh, ll;
    hh.x = f2bf(kv.x); ll.x = f2bf(kv.x - bf2f(hh.x));
    hh.y = f2bf(kv.y); ll.y = f2bf(kv.y - bf2f(hh.y));
    hh.z = f2bf(kv.z); ll.z = f2bf(kv.z - bf2f(hh.z));
    hh.w = f2bf(kv.w); ll.w = f2bf(kv.w - bf2f(hh.w));
    *reinterpret_cast<ushort4*>(KsH + kaddr(j, d0)) = hh;
    *reinterpret_cast<ushort4*>(KsL + kaddr(j, d0)) = ll;
  }

  // ---- stage V transposed: Vt[d][j] bf16, packed pair writes ----
#pragma unroll
  for (int p = 0; p < 4; ++p) {
    const int item = p * 256 + tid;       // 0..1023
    const int jp = item >> 4;             // 0..63 (pair of j)
    const int d0 = (item & 15) << 2;      // 0..60
    const int g0 = lb - 64 + 2 * jp;
    float4 va = make_float4(0.f, 0.f, 0.f, 0.f);
    float4 vb = make_float4(0.f, 0.f, 0.f, 0.f);
    if (g0 >= 0) va = *reinterpret_cast<const float4*>(&Vb[((size_t)g0 << 6) + d0]);
    if (g0 + 1 >= 0) vb = *reinterpret_cast<const float4*>(&Vb[((size_t)(g0 + 1) << 6) + d0]);
    const float aa[4] = {va.x, va.y, va.z, va.w};
    const float bb[4] = {vb.x, vb.y, vb.z, vb.w};
#pragma unroll
    for (int e = 0; e < 4; ++e) {
      const unsigned int pk = (unsigned int)f2bf(aa[e]) | ((unsigned int)f2bf(bb[e]) << 16);
      *reinterpret_cast<unsigned int*>(VtB + taddr(d0 + e, 2 * jp)) = pk;
    }
  }
  __syncthreads();

  // ---- Q fragments (hi/lo split, scale folded in) ----
  const int rtbase = wave * 16;
  const float* qrow = Q + ((size_t)bh << 16) + ((size_t)(lb + rtbase + lr) << 6);
  BF8 qh[2], ql[2];
#pragma unroll
  for (int ks = 0; ks < 2; ++ks) {
    const int d0 = ks * 32 + lg * 8;
    const float4 a = *reinterpret_cast<const float4*>(&qrow[d0]);
    const float4 b = *reinterpret_cast<const float4*>(&qrow[d0 + 4]);
    const float vv[8] = {a.x, a.y, a.z, a.w, b.x, b.y, b.z, b.w};
#pragma unroll
    for (int e = 0; e < 8; ++e) {
      const float v = vv[e] * 0.125f;
      const unsigned short h = f2bf(v);
      qh[ks].u[e] = h;
      ql[ks].u[e] = f2bf(v - bf2f(h));
    }
  }

  // ---- scores: S[rt][j], wave owns rows rtbase..rtbase+15, all 128 j ----
  f32x4 acc[8] = {};
#pragma unroll
  for (int ks = 0; ks < 2; ++ks) {
    const int d0 = ks * 32 + lg * 8;
#pragma unroll
    for (int nt = 0; nt < 8; ++nt) {
      const int j = nt * 16 + lr;
      const bf16x8 kh = *reinterpret_cast<const bf16x8*>(KsH + kaddr(j, d0));
      const bf16x8 kl = *reinterpret_cast<const bf16x8*>(KsL + kaddr(j, d0));
      acc[nt] = __builtin_amdgcn_mfma_f32_16x16x32_bf16(qh[ks].v, kh, acc[nt], 0, 0, 0);
      acc[nt] = __builtin_amdgcn_mfma_f32_16x16x32_bf16(ql[ks].v, kh, acc[nt], 0, 0, 0);
      acc[nt] = __builtin_amdgcn_mfma_f32_16x16x32_bf16(qh[ks].v, kl, acc[nt], 0, 0, 0);
    }
  }

  // ---- masked softmax per row (rows live in 16-lane groups) ----
  float sum4[4];
#pragma unroll
  for (int reg = 0; reg < 4; ++reg) {
    const int rt = rtbase + lg * 4 + reg;
    float m = -3.0e38f;
#pragma unroll
    for (int nt = 0; nt < 8; ++nt) {
      const int j = nt * 16 + lr;
      const bool valid = (j > rt) && (j <= rt + 64);
      const float sv = valid ? acc[nt][reg] : -3.0e38f;
      acc[nt][reg] = sv;
      m = fmaxf(m, sv);
    }
    m = fmaxf(m, __shfl_xor(m, 1));
    m = fmaxf(m, __shfl_xor(m, 2));
    m = fmaxf(m, __shfl_xor(m, 4));
    m = fmaxf(m, __shfl_xor(m, 8));
    float s = 0.f;
#pragma unroll
    for (int nt = 0; nt < 8; ++nt) {
      const float p = (acc[nt][reg] > -1.0e37f) ? __expf(acc[nt][reg] - m) : 0.f;
      acc[nt][reg] = p;
      s += p;
    }
    s += __shfl_xor(s, 1);
    s += __shfl_xor(s, 2);
    s += __shfl_xor(s, 4);
    s += __shfl_xor(s, 8);
    sum4[reg] = s;
  }

  // ---- write P (bf16, swizzled; wave-private rows, no barrier needed) ----
#pragma unroll
  for (int nt = 0; nt < 8; ++nt)
#pragma unroll
    for (int reg = 0; reg < 4; ++reg) {
      const int rt = rtbase + lg * 4 + reg;
      const int j = nt * 16 + lr;
      *reinterpret_cast<unsigned short*>(PsB + taddr(rt, j)) = f2bf(acc[nt][reg]);
    }

  // ---- PV: out[rt][d] = sum_j P[rt][j] * V[j][d] ----
  f32x4 oacc[4] = {};
#pragma unroll
  for (int ks = 0; ks < 4; ++ks) {
    const int j0 = ks * 32 + lg * 8;
    const bf16x8 pa = *reinterpret_cast<const bf16x8*>(PsB + taddr(rtbase + lr, j0));
#pragma unroll
    for (int nt = 0; nt < 4; ++nt) {
      const int d = nt * 16 + lr;
      const bf16x8 vf = *reinterpret_cast<const bf16x8*>(VtB + taddr(d, j0));
      oacc[nt] = __builtin_amdgcn_mfma_f32_16x16x32_bf16(pa, vf, oacc[nt], 0, 0, 0);
    }
  }

  // ---- normalize + write out (bf16, [b][l][h*64+d]) ----
  const int b = bh >> 4, h = bh & 15;
#pragma unroll
  for (int nt = 0; nt < 4; ++nt)
#pragma unroll
    for (int reg = 0; reg < 4; ++reg) {
      const int rt = rtbase + lg * 4 + reg;
      const int d = nt * 16 + lr;
      const float o = oacc[nt][reg] / sum4[reg];
      const int lq = lb + rt;
      O[(((size_t)b * LSEQ + lq) << 10) + (h << 6) + d] = f2bf(o);
    }
}

// ---------------- launch ----------------
extern "C" void kernel_launch(void* const* d_in, const int* in_sizes, int n_in,
                              void* d_out, int out_size, void* d_ws, size_t ws_size,
                              hipStream_t stream) {
  const float* x     = (const float*)d_in[0];
  const float* freqs = (const float*)d_in[1];
  const float* Wq    = (const float*)d_in[2];
  const float* Wk    = (const float*)d_in[3];
  const float* Wv    = (const float*)d_in[4];
  const float* Wo    = (const float*)d_in[5];
  float* out = (float*)d_out;
  char* ws = (char*)d_ws;

  // workspace layout (40 MB total)
  unsigned short* xb  = (unsigned short*)ws;                   // 4 MB: x bf16 [2048][1024]
  unsigned short* Wt  = (unsigned short*)(ws + (4u << 20));    // 8 MB: W^T bf16 x4
  float* QKV          = (float*)(ws + (12u << 20));            // 24 MB: Q,K,V fp32 head-major
  unsigned short* Oat = (unsigned short*)(ws + (36u << 20));   // 4 MB: attn out bf16
  float* ctab = (float*)(ws + (36u << 20) + (1u << 21));       // 128 KB (dead after gemm0)
  float* stab = ctab + 32768;                                  // 128 KB

  prep_all_k<<<6272, 256, 0, stream>>>(x, xb, freqs, ctab, stab, Wq, Wk, Wv, Wo, Wt);

  // Q,K,V = x @ {Wq,Wk,Wv} with fused RoPE (z<2), scattered to head-major fp32
  gemm_bf16_k<0, 128><<<dim3(128, 1, 3), 256, 0, stream>>>(xb, Wt, QKV, ctab, stab);

  // local attention -> bf16 [B*L][D_MODEL]
  local_attn3_k<<<512, 256, 0, stream>>>(QKV, QKV + (1u << 21), QKV + (2u << 21), Oat);

  // final projection -> fp32 d_out (64x128 tiles -> 256 workgroups, 1/CU)
  gemm_bf16_k<1, 64><<<dim3(256, 1, 1), 256, 0, stream>>>(Oat, Wt + (3u << 20), out, ctab, stab);
}